// Round 6
// baseline (57.563 us; speedup 1.0000x reference)
//
#include <hip/hip_runtime.h>
#include <hip/hip_bf16.h>

#define BB 8
#define NN 8192
#define DD 128
#define HH 8
#define KQ 64
#define SPLIT 64
#define NPB (NN / SPLIT)   // 128 rows per gram block

typedef __attribute__((ext_vector_type(8))) short s16x8;
typedef __attribute__((ext_vector_type(4))) float f32x4;
typedef __attribute__((ext_vector_type(4))) unsigned short u16x4;
typedef __attribute__((ext_vector_type(8))) unsigned short u16x8;

// round-to-nearest-even f32 -> bf16 (bit trick)
__device__ __forceinline__ unsigned short bfr(float f) {
  unsigned u = __builtin_bit_cast(unsigned, f);
  u += 0x7fffu + ((u >> 16) & 1u);
  return (unsigned short)(u >> 16);
}
__device__ __forceinline__ float b2f(unsigned short u) {
  unsigned v = (unsigned)u << 16;
  return __builtin_bit_cast(float, v);
}

// ---------- Stage 1: partial Gram via MFMA, depth-2 pipelined loads ----------
// 256 threads / 4 waves; 512 blocks (2/CU). LDS xt[d=128][n=32] bf16,
// 64B rows of 4x16B slots, swizzle slot ^= (d>>1)&3 (2-way = free).
// part written bf16 in register-native permuted layout (coalesced u16x4).
__global__ __launch_bounds__(256) void gram_mfma(
    const float* __restrict__ x, unsigned short* __restrict__ part) {
  const int s = blockIdx.x, b = blockIdx.y;
  const int t = threadIdx.x, l = t & 63, w = t >> 6;
  __shared__ __align__(16) unsigned short xt[2][128 * 32];
  const float* xb = x + ((size_t)b * NN + (size_t)s * NPB) * DD;

  // staging: thread covers d = sd+16i (i<8), n = sn, sn+1  (n tile = 32)
  const int sd = t & 15;
  const int sn = (t >> 4) * 2;

  f32x4 acc[4][4];
#pragma unroll
  for (int i = 0; i < 4; ++i)
#pragma unroll
    for (int j = 0; j < 4; ++j) acc[i][j] = (f32x4){0.f, 0.f, 0.f, 0.f};

  float rv[2][8][2];
  auto load = [&](int slot2, int sub) {
    const float* xs = xb + (size_t)sub * 32 * DD;
#pragma unroll
    for (int i = 0; i < 8; ++i)
#pragma unroll
      for (int j = 0; j < 2; ++j)
        rv[slot2][i][j] = xs[(size_t)(sn + j) * DD + sd + 16 * i];
  };
  auto stage = [&](int buf, int slot2) {
    const int slot = sn >> 3;
#pragma unroll
    for (int i = 0; i < 8; ++i) {
      const int d = sd + 16 * i;
      unsigned v = (unsigned)bfr(rv[slot2][i][0]) |
                   ((unsigned)bfr(rv[slot2][i][1]) << 16);
      char* dst = (char*)&xt[buf][0] + d * 64 +
                  (((slot ^ ((d >> 1) & 3)) << 4) | ((sn & 7) * 2));
      *(unsigned*)dst = v;
    }
  };

  const int nsub = NPB / 32;  // 4
  load(0, 0);
  load(1, 1);
  stage(0, 0);
  __syncthreads();

  const int d1s = (w & 1) * 64, d2s = (w >> 1) * 64;
  const int lr = l & 15, lk = l >> 4;

#pragma unroll
  for (int sub = 0; sub < nsub; ++sub) {
    const int cur = sub & 1;
    if (sub + 2 < nsub) load(sub & 1, sub + 2);  // issue-early (depth 2)
    {
      s16x8 af[4], bv[4];
#pragma unroll
      for (int i = 0; i < 4; ++i) {
        const int row = d1s + i * 16 + lr;
        af[i] = *(const s16x8*)((const char*)&xt[cur][0] + row * 64 +
                                ((lk ^ ((row >> 1) & 3)) << 4));
      }
#pragma unroll
      for (int j = 0; j < 4; ++j) {
        const int row = d2s + j * 16 + lr;
        bv[j] = *(const s16x8*)((const char*)&xt[cur][0] + row * 64 +
                                ((lk ^ ((row >> 1) & 3)) << 4));
      }
#pragma unroll
      for (int i = 0; i < 4; ++i)
#pragma unroll
        for (int j = 0; j < 4; ++j)
          acc[i][j] =
              __builtin_amdgcn_mfma_f32_16x16x32_bf16(af[i], bv[j], acc[i][j], 0, 0, 0);
    }
    if (sub + 1 < nsub) stage(cur ^ 1, (sub + 1) & 1);
    __syncthreads();
  }

  // permuted coalesced store: slot = ((w*16 + i*4 + j)*64 + l) -> u16x4
  unsigned short* gdst = part + (((size_t)b * SPLIT + s) << 14);
#pragma unroll
  for (int i = 0; i < 4; ++i)
#pragma unroll
    for (int j = 0; j < 4; ++j) {
      u16x4 o = {bfr(acc[i][j][0]), bfr(acc[i][j][1]),
                 bfr(acc[i][j][2]), bfr(acc[i][j][3])};
      *(u16x4*)(gdst + ((w * 16 + i * 4 + j) * 64 + l) * 4) = o;
    }
}

// ---------- Stage 2: reduce partials -> Gbf + weight prep (merged) ----------
// grid (24, 8): bx<16 reduce slice for b=by; bx>=16: prep chunk (bx-16)*8+by.
__global__ __launch_bounds__(256) void redprep(
    const unsigned short* __restrict__ part, unsigned short* __restrict__ Gbf,
    const float* __restrict__ Wk, const float* __restrict__ Wq,
    const float* __restrict__ Wv, unsigned short* __restrict__ Wkbf,
    unsigned short* __restrict__ Wvbf, unsigned short* __restrict__ Wqt) {
  const int bx = blockIdx.x, by = blockIdx.y, t = threadIdx.x;
  if (bx < 16) {
    const int b = by;
    const int fidx = bx * 1024 + t * 4;
    const unsigned short* p = part + ((size_t)b * SPLIT << 14) + fidx;
    float s0 = 0.f, s1 = 0.f, s2 = 0.f, s3 = 0.f;
    for (int i = 0; i < SPLIT; ++i) {
      u16x4 v = *(const u16x4*)(p + ((size_t)i << 14));
      s0 += b2f(v[0]); s1 += b2f(v[1]); s2 += b2f(v[2]); s3 += b2f(v[3]);
    }
    // decode permuted slot -> (row, col)
    const int q = fidx >> 2;
    const int l = q & 63, u = q >> 6;
    const int j = u & 3, i = (u >> 2) & 3, w = u >> 4;
    const int lr = l & 15, lk = l >> 4;
    const int row0 = (w & 1) * 64 + i * 16 + lk * 4;
    const int col = (w >> 1) * 64 + j * 16 + lr;
    unsigned short* g = Gbf + ((size_t)b << 14);
    g[(row0 + 0) * 128 + col] = bfr(s0);
    g[(row0 + 1) * 128 + col] = bfr(s1);
    g[(row0 + 2) * 128 + col] = bfr(s2);
    g[(row0 + 3) * 128 + col] = bfr(s3);
    return;
  }
  const int c = (bx - 16) * 8 + by;  // 0..63
  if (c < 16) {                      // Wk -> bf16 (16 chunks x 4096)
    const int base = c * 4096;
#pragma unroll
    for (int q = 0; q < 4; ++q) {
      const int i = base + q * 1024 + t * 4;
      float4 v = *(const float4*)(Wk + i);
      u16x4 o = {bfr(v.x), bfr(v.y), bfr(v.z), bfr(v.w)};
      *(u16x4*)(Wkbf + i) = o;
    }
  } else if (c < 48) {               // Wv -> bf16 (32 chunks x 4096)
    const int base = (c - 16) * 4096;
#pragma unroll
    for (int q = 0; q < 4; ++q) {
      const int i = base + q * 1024 + t * 4;
      float4 v = *(const float4*)(Wv + i);
      u16x4 o = {bfr(v.x), bfr(v.y), bfr(v.z), bfr(v.w)};
      *(u16x4*)(Wvbf + i) = o;
    }
  } else {                           // Wq -> Wqt[h][d][k] transpose (16 chunks)
    const int c2 = c - 48;
    const int h = c2 >> 1, piece = c2 & 1;
    const int d4 = (t & 31) * 4;
#pragma unroll
    for (int p = 0; p < 4; ++p) {
      const int k = piece * 32 + (t >> 5) * 4 + p;
      float4 v = *(const float4*)(Wq + (size_t)h * 8192 + k * DD + d4);
      unsigned short* dst = Wqt + (size_t)h * 8192;
      dst[(d4 + 0) * KQ + k] = bfr(v.x);
      dst[(d4 + 1) * KQ + k] = bfr(v.y);
      dst[(d4 + 2) * KQ + k] = bfr(v.z);
      dst[(d4 + 3) * KQ + k] = bfr(v.w);
    }
  }
}

// ---------- Stage 3 (fused): Mp[b,h] = (Wq^T (Wk G Wv^T))^T contribution ----------
__global__ __launch_bounds__(256) void middle_fused(
    const unsigned short* __restrict__ Gbf, const unsigned short* __restrict__ Wkbf,
    const unsigned short* __restrict__ Wvbf, const unsigned short* __restrict__ Wqt,
    float* __restrict__ Mp) {
  const int b = blockIdx.x >> 3, h = blockIdx.x & 7;
  const int t = threadIdx.x, l = t & 63, w = t >> 6;
  const int lr = l & 15, lk = l >> 4;
  __shared__ __align__(16) unsigned short Gs[128 * 128];
  __shared__ __align__(16) unsigned short T1s[64 * 128];
  __shared__ __align__(16) unsigned short T2t[128 * 64];

  const unsigned short* gsrc = Gbf + ((size_t)b << 14);
#pragma unroll
  for (int c8 = 0; c8 < 8; ++c8) {
    const int c = t + c8 * 256;
    const int row = c >> 4, slot = c & 15;
    u16x8 v = *(const u16x8*)(gsrc + row * 128 + slot * 8);
    *(u16x8*)(&Gs[row * 128 + ((slot ^ (row & 15)) << 3)]) = v;
  }
  __syncthreads();

  // ---- stage A: T1 = Wk[h] @ G ----
  const unsigned short* wk = Wkbf + ((size_t)h << 13);
  s16x8 aw[4];
#pragma unroll
  for (int ks = 0; ks < 4; ++ks)
    aw[ks] = *(const s16x8*)(wk + ((w * 16 + lr) << 7) + ks * 32 + lk * 8);
  f32x4 accA[8];
#pragma unroll
  for (int j = 0; j < 8; ++j) accA[j] = (f32x4){0.f, 0.f, 0.f, 0.f};
#pragma unroll
  for (int nj = 0; nj < 8; ++nj)
#pragma unroll
    for (int ks = 0; ks < 4; ++ks) {
      const int row = nj * 16 + lr;
      const int slot = (ks * 4 + lk) ^ (row & 15);
      s16x8 bfrag = *(const s16x8*)(&Gs[(row << 7) + (slot << 3)]);
      accA[nj] = __builtin_amdgcn_mfma_f32_16x16x32_bf16(aw[ks], bfrag, accA[nj], 0, 0, 0);
    }
#pragma unroll
  for (int nj = 0; nj < 8; ++nj)
#pragma unroll
    for (int r = 0; r < 4; ++r) {
      const int row = w * 16 + lk * 4 + r;
      const int col = nj * 16 + lr;
      const int slot = (col >> 3) ^ (row & 15);
      T1s[(row << 7) + (slot << 3) + (col & 7)] = bfr(accA[nj][r]);
    }
  __syncthreads();

  // ---- stage B: T2 = T1 @ Wv^T ----
  s16x8 a2[4];
#pragma unroll
  for (int ks = 0; ks < 4; ++ks) {
    const int row = w * 16 + lr;
    const int slot = (ks * 4 + lk) ^ (row & 15);
    a2[ks] = *(const s16x8*)(&T1s[(row << 7) + (slot << 3)]);
  }
  const unsigned short* wv = Wvbf + ((size_t)h << 14);
  f32x4 accB[8];
#pragma unroll
  for (int j = 0; j < 8; ++j) accB[j] = (f32x4){0.f, 0.f, 0.f, 0.f};
#pragma unroll
  for (int nj = 0; nj < 8; ++nj)
#pragma unroll
    for (int ks = 0; ks < 4; ++ks) {
      s16x8 bfrag = *(const s16x8*)(wv + (((size_t)(nj * 16 + lr)) << 7) + ks * 32 + lk * 8);
      accB[nj] = __builtin_amdgcn_mfma_f32_16x16x32_bf16(a2[ks], bfrag, accB[nj], 0, 0, 0);
    }
#pragma unroll
  for (int nj = 0; nj < 8; ++nj)
#pragma unroll
    for (int r = 0; r < 4; ++r) {
      const int e = nj * 16 + lr;
      const int k = w * 16 + lk * 4 + r;
      const int slot = (k >> 3) ^ (e & 7);
      T2t[(e << 6) + (slot << 3) + (k & 7)] = bfr(accB[nj][r]);
    }
  __syncthreads();

  // ---- stage C: M^T contrib = T2^T @ Wq ----
  const unsigned short* wq = Wqt + ((size_t)h << 13);
  float* mp = Mp + (((size_t)(b * 8 + h)) << 14);
#pragma unroll
  for (int p = 0; p < 2; ++p) {
    s16x8 a3[2];
#pragma unroll
    for (int ks = 0; ks < 2; ++ks) {
      const int row = (2 * w + p) * 16 + lr;
      const int slot = (ks * 4 + lk) ^ (row & 7);
      a3[ks] = *(const s16x8*)(&T2t[(row << 6) + (slot << 3)]);
    }
    f32x4 accC[8];
#pragma unroll
    for (int j = 0; j < 8; ++j) accC[j] = (f32x4){0.f, 0.f, 0.f, 0.f};
#pragma unroll
    for (int nj = 0; nj < 8; ++nj)
#pragma unroll
      for (int ks = 0; ks < 2; ++ks) {
        s16x8 bfrag = *(const s16x8*)(wq + ((nj * 16 + lr) << 6) + ks * 32 + lk * 8);
        accC[nj] = __builtin_amdgcn_mfma_f32_16x16x32_bf16(a3[ks], bfrag, accC[nj], 0, 0, 0);
      }
#pragma unroll
    for (int nj = 0; nj < 8; ++nj)
#pragma unroll
      for (int r = 0; r < 4; ++r) {
        const int row = (2 * w + p) * 16 + lk * 4 + r;
        const int col = nj * 16 + lr;
        mp[(row << 7) + col] = accC[nj][r];
      }
  }
}

// ---------- Stage 3d: Mt[b][e][d] = bf16( sum_h Mp[b][h][e][d] ) ----------
__global__ __launch_bounds__(256) void m_reduce_t(
    const float* __restrict__ Mp, unsigned short* __restrict__ Mt) {
  const int b = blockIdx.y;
  const int idx = blockIdx.x * 1024 + threadIdx.x * 4;
  float4 s = {0.f, 0.f, 0.f, 0.f};
#pragma unroll
  for (int h = 0; h < 8; ++h) {
    float4 v = *(const float4*)(Mp + (((size_t)(b * 8 + h)) << 14) + idx);
    s.x += v.x; s.y += v.y; s.z += v.z; s.w += v.w;
  }
  u16x4 o = {bfr(s.x), bfr(s.y), bfr(s.z), bfr(s.w)};
  *(u16x4*)(Mt + ((size_t)b << 14) + idx) = o;
}

// ---------- Stage 4: out[b] = X[b] @ M[b] via MFMA ----------
// No LDS: B-frags read Mt[e][d] (bf16, L2-hot) directly; A from fp32 x + cvt.
// 128-thr blocks (2 waves), 32-row tiles, grid 2048 (8 blocks/CU).
__global__ __launch_bounds__(128) void out_mfma(
    const float* __restrict__ x, const unsigned short* __restrict__ Mt,
    float* __restrict__ out) {
  const int b = blockIdx.y, t = threadIdx.x, l = t & 63, w = t >> 6;
  const int lr = l & 15, lk = l >> 4;
  const int rw = blockIdx.x * 32 + w * 16;
  const unsigned short* mb = Mt + ((size_t)b << 14);

  f32x4 acc[8];
#pragma unroll
  for (int j = 0; j < 8; ++j) acc[j] = (f32x4){0.f, 0.f, 0.f, 0.f};

  const float* xb = x + (size_t)b * NN * DD;
#pragma unroll
  for (int ks = 0; ks < 4; ++ks) {
    const float* p = xb + (size_t)(rw + lr) * DD + ks * 32 + lk * 8;
    float4 v0 = *(const float4*)p;
    float4 v1 = *(const float4*)(p + 4);
    s16x8 af;
    af[0] = (short)bfr(v0.x); af[1] = (short)bfr(v0.y);
    af[2] = (short)bfr(v0.z); af[3] = (short)bfr(v0.w);
    af[4] = (short)bfr(v1.x); af[5] = (short)bfr(v1.y);
    af[6] = (short)bfr(v1.z); af[7] = (short)bfr(v1.w);
#pragma unroll
    for (int j = 0; j < 8; ++j) {
      s16x8 bv = *(const s16x8*)(mb + (j * 16 + lr) * DD + ks * 32 + lk * 8);
      acc[j] = __builtin_amdgcn_mfma_f32_16x16x32_bf16(af, bv, acc[j], 0, 0, 0);
    }
  }

  float* ob = out + (size_t)b * NN * DD;
#pragma unroll
  for (int j = 0; j < 8; ++j)
#pragma unroll
    for (int r = 0; r < 4; ++r) {
      const int row = rw + lk * 4 + r;
      const int col = j * 16 + lr;
      ob[(size_t)row * DD + col] = acc[j][r];
    }
}

extern "C" void kernel_launch(void* const* d_in, const int* in_sizes, int n_in,
                              void* d_out, int out_size, void* d_ws, size_t ws_size,
                              hipStream_t stream) {
  const float* x  = (const float*)d_in[0];
  const float* Wk = (const float*)d_in[1];
  const float* Wq = (const float*)d_in[2];
  const float* Wv = (const float*)d_in[3];
  float* out = (float*)d_out;
  float* ws  = (float*)d_ws;

  // workspace layout (float slots, all 16B-aligned)
  const size_t off_Mp   = 0;                                         // 8*8*16384 fp32
  const size_t off_part = off_Mp + (size_t)BB * HH * DD * DD;        // bf16: 8*64*16384 u16
  const size_t off_Gbf  = off_part + (size_t)BB * SPLIT * DD * DD / 2;
  const size_t off_Mt   = off_Gbf + (size_t)BB * DD * DD / 2;
  const size_t off_Wkbf = off_Mt + (size_t)BB * DD * DD / 2;
  const size_t off_Wvbf = off_Wkbf + (size_t)HH * KQ * DD / 2;
  const size_t off_Wqt  = off_Wvbf + (size_t)HH * DD * DD / 2;

  float* Mp   = ws + off_Mp;
  unsigned short* part = (unsigned short*)(ws + off_part);
  unsigned short* Gbf  = (unsigned short*)(ws + off_Gbf);
  unsigned short* Mt   = (unsigned short*)(ws + off_Mt);
  unsigned short* Wkbf = (unsigned short*)(ws + off_Wkbf);
  unsigned short* Wvbf = (unsigned short*)(ws + off_Wvbf);
  unsigned short* Wqt  = (unsigned short*)(ws + off_Wqt);

  gram_mfma<<<dim3(SPLIT, BB), 256, 0, stream>>>(x, part);
  redprep<<<dim3(24, BB), 256, 0, stream>>>(part, Gbf, Wk, Wq, Wv, Wkbf, Wvbf, Wqt);
  middle_fused<<<64, 256, 0, stream>>>(Gbf, Wkbf, Wvbf, Wqt, Mp);
  m_reduce_t<<<dim3(16, BB), 256, 0, stream>>>(Mp, Mt);
  out_mfma<<<dim3(NN / 32, BB), 128, 0, stream>>>(x, Mt, out);
}

// Round 7
// 47.140 us; speedup vs baseline: 1.2211x; 1.2211x over previous
//
#include <hip/hip_runtime.h>
#include <hip/hip_bf16.h>

#define BB 8
#define NN 8192
#define DD 128
#define HH 8
#define KQ 64
#define SPLIT 64
#define NPB (NN / SPLIT)   // 128 rows per gram block

typedef __attribute__((ext_vector_type(8))) short s16x8;
typedef __attribute__((ext_vector_type(4))) float f32x4;
typedef __attribute__((ext_vector_type(4))) unsigned short u16x4;
typedef __attribute__((ext_vector_type(8))) unsigned short u16x8;

// round-to-nearest-even f32 -> bf16 (bit trick)
__device__ __forceinline__ unsigned short bfr(float f) {
  unsigned u = __builtin_bit_cast(unsigned, f);
  u += 0x7fffu + ((u >> 16) & 1u);
  return (unsigned short)(u >> 16);
}
__device__ __forceinline__ float b2f(unsigned short u) {
  unsigned v = (unsigned)u << 16;
  return __builtin_bit_cast(float, v);
}

// ---------- Stage 1: partial Gram via MFMA (R5-proven version) ----------
// 256 threads / 4 waves; 512 blocks (2/CU). LDS xt[d=128][n=32] bf16,
// 64B rows of 4x16B slots, swizzle slot ^= (d>>1)&3 (2-way = free).
// part written bf16 in register-native permuted layout (coalesced u16x4).
__global__ __launch_bounds__(256) void gram_mfma(
    const float* __restrict__ x, unsigned short* __restrict__ part) {
  const int s = blockIdx.x, b = blockIdx.y;
  const int t = threadIdx.x, l = t & 63, w = t >> 6;
  __shared__ __align__(16) unsigned short xt[2][128 * 32];
  const float* xb = x + ((size_t)b * NN + (size_t)s * NPB) * DD;

  // staging: thread covers d = sd+16i (i<8), n = sn, sn+1  (n tile = 32)
  const int sd = t & 15;
  const int sn = (t >> 4) * 2;

  f32x4 acc[4][4];
#pragma unroll
  for (int i = 0; i < 4; ++i)
#pragma unroll
    for (int j = 0; j < 4; ++j) acc[i][j] = (f32x4){0.f, 0.f, 0.f, 0.f};

  float rv[8][2];
  auto load = [&](int sub) {
    const float* xs = xb + (size_t)sub * 32 * DD;
#pragma unroll
    for (int i = 0; i < 8; ++i)
#pragma unroll
      for (int j = 0; j < 2; ++j)
        rv[i][j] = xs[(size_t)(sn + j) * DD + sd + 16 * i];
  };
  auto stage = [&](int buf) {
    const int slot = sn >> 3;
#pragma unroll
    for (int i = 0; i < 8; ++i) {
      const int d = sd + 16 * i;
      unsigned v = (unsigned)bfr(rv[i][0]) | ((unsigned)bfr(rv[i][1]) << 16);
      char* dst = (char*)&xt[buf][0] + d * 64 +
                  (((slot ^ ((d >> 1) & 3)) << 4) | ((sn & 7) * 2));
      *(unsigned*)dst = v;
    }
  };

  load(0);
  stage(0);
  __syncthreads();

  const int d1s = (w & 1) * 64, d2s = (w >> 1) * 64;
  const int lr = l & 15, lk = l >> 4;
  const int nsub = NPB / 32;  // 4

  for (int sub = 0; sub < nsub; ++sub) {
    const int cur = sub & 1;
    if (sub + 1 < nsub) load(sub + 1);
    {
      s16x8 af[4], bv[4];
#pragma unroll
      for (int i = 0; i < 4; ++i) {
        const int row = d1s + i * 16 + lr;
        af[i] = *(const s16x8*)((const char*)&xt[cur][0] + row * 64 +
                                ((lk ^ ((row >> 1) & 3)) << 4));
      }
#pragma unroll
      for (int j = 0; j < 4; ++j) {
        const int row = d2s + j * 16 + lr;
        bv[j] = *(const s16x8*)((const char*)&xt[cur][0] + row * 64 +
                                ((lk ^ ((row >> 1) & 3)) << 4));
      }
#pragma unroll
      for (int i = 0; i < 4; ++i)
#pragma unroll
        for (int j = 0; j < 4; ++j)
          acc[i][j] =
              __builtin_amdgcn_mfma_f32_16x16x32_bf16(af[i], bv[j], acc[i][j], 0, 0, 0);
    }
    if (sub + 1 < nsub) stage(cur ^ 1);
    __syncthreads();
  }

  // permuted coalesced store: slot = ((w*16 + i*4 + j)*64 + l) -> u16x4
  unsigned short* gdst = part + (((size_t)b * SPLIT + s) << 14);
#pragma unroll
  for (int i = 0; i < 4; ++i)
#pragma unroll
    for (int j = 0; j < 4; ++j) {
      u16x4 o = {bfr(acc[i][j][0]), bfr(acc[i][j][1]),
                 bfr(acc[i][j][2]), bfr(acc[i][j][3])};
      *(u16x4*)(gdst + ((w * 16 + i * 4 + j) * 64 + l) * 4) = o;
    }
}

// ---------- Stage 2: reduce partials -> Gbf + weight prep (merged) ----------
// grid (24, 8): bx<16 reduce slice for b=by; bx>=16: prep chunk (bx-16)*8+by.
__global__ __launch_bounds__(256) void redprep(
    const unsigned short* __restrict__ part, unsigned short* __restrict__ Gbf,
    const float* __restrict__ Wk, const float* __restrict__ Wq,
    const float* __restrict__ Wv, unsigned short* __restrict__ Wkbf,
    unsigned short* __restrict__ Wvbf, unsigned short* __restrict__ Wqt) {
  const int bx = blockIdx.x, by = blockIdx.y, t = threadIdx.x;
  if (bx < 16) {
    const int b = by;
    const int fidx = bx * 1024 + t * 4;
    const unsigned short* p = part + ((size_t)b * SPLIT << 14) + fidx;
    float s0 = 0.f, s1 = 0.f, s2 = 0.f, s3 = 0.f;
    for (int i = 0; i < SPLIT; ++i) {
      u16x4 v = *(const u16x4*)(p + ((size_t)i << 14));
      s0 += b2f(v[0]); s1 += b2f(v[1]); s2 += b2f(v[2]); s3 += b2f(v[3]);
    }
    // decode permuted slot -> (row, col)
    const int q = fidx >> 2;
    const int l = q & 63, u = q >> 6;
    const int j = u & 3, i = (u >> 2) & 3, w = u >> 4;
    const int lr = l & 15, lk = l >> 4;
    const int row0 = (w & 1) * 64 + i * 16 + lk * 4;
    const int col = (w >> 1) * 64 + j * 16 + lr;
    unsigned short* g = Gbf + ((size_t)b << 14);
    g[(row0 + 0) * 128 + col] = bfr(s0);
    g[(row0 + 1) * 128 + col] = bfr(s1);
    g[(row0 + 2) * 128 + col] = bfr(s2);
    g[(row0 + 3) * 128 + col] = bfr(s3);
    return;
  }
  const int c = (bx - 16) * 8 + by;  // 0..63
  if (c < 16) {                      // Wk -> bf16 (16 chunks x 4096)
    const int base = c * 4096;
#pragma unroll
    for (int q = 0; q < 4; ++q) {
      const int i = base + q * 1024 + t * 4;
      float4 v = *(const float4*)(Wk + i);
      u16x4 o = {bfr(v.x), bfr(v.y), bfr(v.z), bfr(v.w)};
      *(u16x4*)(Wkbf + i) = o;
    }
  } else if (c < 48) {               // Wv -> bf16 (32 chunks x 4096)
    const int base = (c - 16) * 4096;
#pragma unroll
    for (int q = 0; q < 4; ++q) {
      const int i = base + q * 1024 + t * 4;
      float4 v = *(const float4*)(Wv + i);
      u16x4 o = {bfr(v.x), bfr(v.y), bfr(v.z), bfr(v.w)};
      *(u16x4*)(Wvbf + i) = o;
    }
  } else {                           // Wq -> Wqt[h][d][k] transpose (16 chunks)
    const int c2 = c - 48;
    const int h = c2 >> 1, piece = c2 & 1;
    const int d4 = (t & 31) * 4;
#pragma unroll
    for (int p = 0; p < 4; ++p) {
      const int k = piece * 32 + (t >> 5) * 4 + p;
      float4 v = *(const float4*)(Wq + (size_t)h * 8192 + k * DD + d4);
      unsigned short* dst = Wqt + (size_t)h * 8192;
      dst[(d4 + 0) * KQ + k] = bfr(v.x);
      dst[(d4 + 1) * KQ + k] = bfr(v.y);
      dst[(d4 + 2) * KQ + k] = bfr(v.z);
      dst[(d4 + 3) * KQ + k] = bfr(v.w);
    }
  }
}

// ---------- Stage 3 (fused): Mp[b,h] = (Wq^T (Wk G Wv^T))^T contribution ----------
__global__ __launch_bounds__(256) void middle_fused(
    const unsigned short* __restrict__ Gbf, const unsigned short* __restrict__ Wkbf,
    const unsigned short* __restrict__ Wvbf, const unsigned short* __restrict__ Wqt,
    float* __restrict__ Mp) {
  const int b = blockIdx.x >> 3, h = blockIdx.x & 7;
  const int t = threadIdx.x, l = t & 63, w = t >> 6;
  const int lr = l & 15, lk = l >> 4;
  __shared__ __align__(16) unsigned short Gs[128 * 128];
  __shared__ __align__(16) unsigned short T1s[64 * 128];
  __shared__ __align__(16) unsigned short T2t[128 * 64];

  const unsigned short* gsrc = Gbf + ((size_t)b << 14);
#pragma unroll
  for (int c8 = 0; c8 < 8; ++c8) {
    const int c = t + c8 * 256;
    const int row = c >> 4, slot = c & 15;
    u16x8 v = *(const u16x8*)(gsrc + row * 128 + slot * 8);
    *(u16x8*)(&Gs[row * 128 + ((slot ^ (row & 15)) << 3)]) = v;
  }
  __syncthreads();

  // ---- stage A: T1 = Wk[h] @ G ----
  const unsigned short* wk = Wkbf + ((size_t)h << 13);
  s16x8 aw[4];
#pragma unroll
  for (int ks = 0; ks < 4; ++ks)
    aw[ks] = *(const s16x8*)(wk + ((w * 16 + lr) << 7) + ks * 32 + lk * 8);
  f32x4 accA[8];
#pragma unroll
  for (int j = 0; j < 8; ++j) accA[j] = (f32x4){0.f, 0.f, 0.f, 0.f};
#pragma unroll
  for (int nj = 0; nj < 8; ++nj)
#pragma unroll
    for (int ks = 0; ks < 4; ++ks) {
      const int row = nj * 16 + lr;
      const int slot = (ks * 4 + lk) ^ (row & 15);
      s16x8 bfrag = *(const s16x8*)(&Gs[(row << 7) + (slot << 3)]);
      accA[nj] = __builtin_amdgcn_mfma_f32_16x16x32_bf16(aw[ks], bfrag, accA[nj], 0, 0, 0);
    }
#pragma unroll
  for (int nj = 0; nj < 8; ++nj)
#pragma unroll
    for (int r = 0; r < 4; ++r) {
      const int row = w * 16 + lk * 4 + r;
      const int col = nj * 16 + lr;
      const int slot = (col >> 3) ^ (row & 15);
      T1s[(row << 7) + (slot << 3) + (col & 7)] = bfr(accA[nj][r]);
    }
  __syncthreads();

  // ---- stage B: T2 = T1 @ Wv^T ----
  s16x8 a2[4];
#pragma unroll
  for (int ks = 0; ks < 4; ++ks) {
    const int row = w * 16 + lr;
    const int slot = (ks * 4 + lk) ^ (row & 15);
    a2[ks] = *(const s16x8*)(&T1s[(row << 7) + (slot << 3)]);
  }
  const unsigned short* wv = Wvbf + ((size_t)h << 14);
  f32x4 accB[8];
#pragma unroll
  for (int j = 0; j < 8; ++j) accB[j] = (f32x4){0.f, 0.f, 0.f, 0.f};
#pragma unroll
  for (int nj = 0; nj < 8; ++nj)
#pragma unroll
    for (int ks = 0; ks < 4; ++ks) {
      s16x8 bfrag = *(const s16x8*)(wv + (((size_t)(nj * 16 + lr)) << 7) + ks * 32 + lk * 8);
      accB[nj] = __builtin_amdgcn_mfma_f32_16x16x32_bf16(a2[ks], bfrag, accB[nj], 0, 0, 0);
    }
#pragma unroll
  for (int nj = 0; nj < 8; ++nj)
#pragma unroll
    for (int r = 0; r < 4; ++r) {
      const int e = nj * 16 + lr;
      const int k = w * 16 + lk * 4 + r;
      const int slot = (k >> 3) ^ (e & 7);
      T2t[(e << 6) + (slot << 3) + (k & 7)] = bfr(accB[nj][r]);
    }
  __syncthreads();

  // ---- stage C: M^T contrib = T2^T @ Wq ----
  const unsigned short* wq = Wqt + ((size_t)h << 13);
  float* mp = Mp + (((size_t)(b * 8 + h)) << 14);
#pragma unroll
  for (int p = 0; p < 2; ++p) {
    s16x8 a3[2];
#pragma unroll
    for (int ks = 0; ks < 2; ++ks) {
      const int row = (2 * w + p) * 16 + lr;
      const int slot = (ks * 4 + lk) ^ (row & 7);
      a3[ks] = *(const s16x8*)(&T2t[(row << 6) + (slot << 3)]);
    }
    f32x4 accC[8];
#pragma unroll
    for (int j = 0; j < 8; ++j) accC[j] = (f32x4){0.f, 0.f, 0.f, 0.f};
#pragma unroll
    for (int nj = 0; nj < 8; ++nj)
#pragma unroll
      for (int ks = 0; ks < 2; ++ks) {
        s16x8 bfrag = *(const s16x8*)(wq + ((nj * 16 + lr) << 6) + ks * 32 + lk * 8);
        accC[nj] = __builtin_amdgcn_mfma_f32_16x16x32_bf16(a3[ks], bfrag, accC[nj], 0, 0, 0);
      }
#pragma unroll
    for (int nj = 0; nj < 8; ++nj)
#pragma unroll
      for (int r = 0; r < 4; ++r) {
        const int row = (2 * w + p) * 16 + lk * 4 + r;
        const int col = nj * 16 + lr;
        mp[(row << 7) + col] = accC[nj][r];
      }
  }
}

// ---------- Stage 3d: Mt[b][e][d] = bf16( sum_h Mp[b][h][e][d] ) ----------
__global__ __launch_bounds__(256) void m_reduce_t(
    const float* __restrict__ Mp, unsigned short* __restrict__ Mt) {
  const int b = blockIdx.y;
  const int idx = blockIdx.x * 1024 + threadIdx.x * 4;
  float4 s = {0.f, 0.f, 0.f, 0.f};
#pragma unroll
  for (int h = 0; h < 8; ++h) {
    float4 v = *(const float4*)(Mp + (((size_t)(b * 8 + h)) << 14) + idx);
    s.x += v.x; s.y += v.y; s.z += v.z; s.w += v.w;
  }
  u16x4 o = {bfr(s.x), bfr(s.y), bfr(s.z), bfr(s.w)};
  *(u16x4*)(Mt + ((size_t)b << 14) + idx) = o;
}

// ---------- Stage 4: out[b] = X[b] @ M[b] via MFMA (R5-proven LDS version) ----------
__global__ __launch_bounds__(256) void out_mfma(
    const float* __restrict__ x, const unsigned short* __restrict__ Mt,
    float* __restrict__ out) {
  const int b = blockIdx.y, t = threadIdx.x, l = t & 63, w = t >> 6;
  const int r0 = blockIdx.x * 64;
  __shared__ __align__(16) unsigned short mt[DD * DD];
  const unsigned short* msrc = Mt + (size_t)b * (DD * DD);
#pragma unroll
  for (int k = 0; k < 8; ++k) {
    const int c = t + k * 256;
    const int e = c >> 4, slot = c & 15;
    u16x8 v = *(const u16x8*)(msrc + e * DD + slot * 8);
    *(u16x8*)(&mt[e * DD + ((slot ^ (e & 15)) << 3)]) = v;
  }
  __syncthreads();

  const int lr = l & 15, lk = l >> 4;
  const int rw = r0 + w * 16;
  f32x4 acc[8];
#pragma unroll
  for (int j = 0; j < 8; ++j) acc[j] = (f32x4){0.f, 0.f, 0.f, 0.f};

  const float* xb = x + (size_t)b * NN * DD;
#pragma unroll
  for (int ks = 0; ks < 4; ++ks) {
    const float* p = xb + (size_t)(rw + lr) * DD + ks * 32 + lk * 8;
    float4 v0 = *(const float4*)p;
    float4 v1 = *(const float4*)(p + 4);
    s16x8 af;
    af[0] = (short)bfr(v0.x); af[1] = (short)bfr(v0.y);
    af[2] = (short)bfr(v0.z); af[3] = (short)bfr(v0.w);
    af[4] = (short)bfr(v1.x); af[5] = (short)bfr(v1.y);
    af[6] = (short)bfr(v1.z); af[7] = (short)bfr(v1.w);
    const int slot = ks * 4 + lk;
#pragma unroll
    for (int j = 0; j < 8; ++j) {
      const int e = j * 16 + lr;
      s16x8 bv = *(const s16x8*)(&mt[e * DD + ((slot ^ (e & 15)) << 3)]);
      acc[j] = __builtin_amdgcn_mfma_f32_16x16x32_bf16(af, bv, acc[j], 0, 0, 0);
    }
  }

  float* ob = out + (size_t)b * NN * DD;
#pragma unroll
  for (int j = 0; j < 8; ++j)
#pragma unroll
    for (int r = 0; r < 4; ++r) {
      const int row = rw + lk * 4 + r;
      const int col = j * 16 + lr;
      ob[(size_t)row * DD + col] = acc[j][r];
    }
}

extern "C" void kernel_launch(void* const* d_in, const int* in_sizes, int n_in,
                              void* d_out, int out_size, void* d_ws, size_t ws_size,
                              hipStream_t stream) {
  const float* x  = (const float*)d_in[0];
  const float* Wk = (const float*)d_in[1];
  const float* Wq = (const float*)d_in[2];
  const float* Wv = (const float*)d_in[3];
  float* out = (float*)d_out;
  float* ws  = (float*)d_ws;

  // workspace layout (float slots, all 16B-aligned)
  const size_t off_Mp   = 0;                                         // 8*8*16384 fp32
  const size_t off_part = off_Mp + (size_t)BB * HH * DD * DD;        // bf16: 8*64*16384 u16
  const size_t off_Gbf  = off_part + (size_t)BB * SPLIT * DD * DD / 2;
  const size_t off_Mt   = off_Gbf + (size_t)BB * DD * DD / 2;
  const size_t off_Wkbf = off_Mt + (size_t)BB * DD * DD / 2;
  const size_t off_Wvbf = off_Wkbf + (size_t)HH * KQ * DD / 2;
  const size_t off_Wqt  = off_Wvbf + (size_t)HH * DD * DD / 2;

  float* Mp   = ws + off_Mp;
  unsigned short* part = (unsigned short*)(ws + off_part);
  unsigned short* Gbf  = (unsigned short*)(ws + off_Gbf);
  unsigned short* Mt   = (unsigned short*)(ws + off_Mt);
  unsigned short* Wkbf = (unsigned short*)(ws + off_Wkbf);
  unsigned short* Wvbf = (unsigned short*)(ws + off_Wvbf);
  unsigned short* Wqt  = (unsigned short*)(ws + off_Wqt);

  gram_mfma<<<dim3(SPLIT, BB), 256, 0, stream>>>(x, part);
  redprep<<<dim3(24, BB), 256, 0, stream>>>(part, Gbf, Wk, Wq, Wv, Wkbf, Wvbf, Wqt);
  middle_fused<<<64, 256, 0, stream>>>(Gbf, Wkbf, Wvbf, Wqt, Mp);
  m_reduce_t<<<dim3(16, BB), 256, 0, stream>>>(Mp, Mt);
  out_mfma<<<dim3(NN / 64, BB), 256, 0, stream>>>(x, Mt, out);
}